// Round 2
// baseline (3631.559 us; speedup 1.0000x reference)
//
#include <hip/hip_runtime.h>
#include <math.h>

#define S_MAX 64
#define D_MAX 128
#define F_MAX 96
#define EPSF 1e-8f
#define NEGF -1e30f

__device__ __forceinline__ float softplusf(float x) {
    // jax.nn.softplus = logaddexp(x, 0) = max(x,0) + log1p(exp(-|x|))
    return fmaxf(x, 0.0f) + log1pf(expf(-fabsf(x)));
}

// ---------------- Kernel 1: params prep (dur_lp, trans, ivar, sum_log_vars) ----
__global__ __launch_bounds__(256)
void prep_kernel(const float* __restrict__ logits,
                 const float* __restrict__ log_vars,
                 const float* __restrict__ shape_p,
                 const float* __restrict__ rate_p,
                 const int* __restrict__ max_d_p, const int* __restrict__ min_d_p,
                 float* __restrict__ dur_lp, float* __restrict__ trans,
                 float* __restrict__ ivar, float* __restrict__ svl,
                 int S, int F) {
    int tid = threadIdx.x;
    int min_d = *min_d_p, max_d = *max_d_p;
    int D = max_d - min_d + 1;
    if (D > D_MAX) D = D_MAX;   // defensive: never exceed static ring capacity

    // inverse variances + per-state sum of log-vars
    for (int s = tid; s < S; s += blockDim.x) {
        float acc = 0.f;
        for (int f = 0; f < F; ++f) {
            float lv = log_vars[s * F + f];
            ivar[s * F + f] = expf(-lv);
            acc += lv;
        }
        svl[s] = acc;
    }
    // duration log-probs: gamma at dval = min_d + di, then log(exp(lp)+eps)
    for (int s = tid; s < S; s += blockDim.x) {
        float a = softplusf(shape_p[s]);
        float r = softplusf(rate_p[s]);
        float lga = lgammaf(a);
        float alr = a * logf(r + EPSF);
        for (int di = 0; di < D; ++di) {
            float dval = (float)(min_d + di);
            float lp = (a - 1.f) * logf(dval + EPSF) - r * dval - lga + alr;
            dur_lp[s * D + di] = logf(expf(lp) + EPSF);
        }
    }
    // transitions: softmax over row with -inf diagonal; log(p+eps); diag=NEG
    for (int p = tid; p < S; p += blockDim.x) {
        float m = -INFINITY;
        for (int j = 0; j < S; ++j)
            if (j != p) m = fmaxf(m, logits[p * S + j]);
        float sum = 0.f;
        for (int j = 0; j < S; ++j)
            if (j != p) sum += expf(logits[p * S + j] - m);
        for (int j = 0; j < S; ++j) {
            float v;
            if (j == p) v = NEGF;
            else v = logf(expf(logits[p * S + j] - m) / sum + EPSF);
            trans[p * S + j] = v;
        }
    }
}

// ---------------- Kernel 2: observation log-probs (B*T, S) -------------------
__global__ __launch_bounds__(256)
void obs_kernel(const float* __restrict__ obs,
                const float* __restrict__ means,
                const float* __restrict__ ivar,
                const float* __restrict__ svl,
                float* __restrict__ obs_lp,
                int BT, int S, int F) {
    __shared__ float sMean[S_MAX * (F_MAX + 1)];
    __shared__ float sIvar[S_MAX * (F_MAX + 1)];
    __shared__ float sObs[4][F_MAX];

    int tid = threadIdx.x + threadIdx.y * 64;
    int PF = F + 1;  // padded stride: breaks bank conflict on s-indexed reads
    for (int i = tid; i < S * F; i += 256) {
        int ss = i / F, ff = i % F;
        sMean[ss * PF + ff] = means[i];
        sIvar[ss * PF + ff] = ivar[i];
    }
    int row0 = blockIdx.x * 4;
    for (int i = tid; i < 4 * F; i += 256) {
        int r = i / F, f = i % F;
        if (row0 + r < BT) sObs[r][f] = obs[(size_t)(row0 + r) * F + f];
    }
    __syncthreads();

    int s = threadIdx.x;
    int r = threadIdx.y;
    int row = row0 + r;
    if (row >= BT || s >= S) return;

    float quad = 0.f;
    const float* mr = &sMean[s * PF];
    const float* vr = &sIvar[s * PF];
    for (int f = 0; f < F; ++f) {
        float d = sObs[r][f] - mr[f];
        quad = fmaf(d * d, vr[f], quad);
    }
    const float LOG2PI = 1.8378770664093453f;
    float lp = -0.5f * (quad + svl[s] + (float)F * LOG2PI);
    obs_lp[(size_t)row * S + s] = lp;
}

// ---------------- Kernel 3: per-batch Viterbi scan + backtrace ---------------
__global__ __launch_bounds__(256)
void viterbi_kernel(const float* __restrict__ obs_lp,
                    const float* __restrict__ dur_lp_g,
                    const float* __restrict__ trans_g,
                    int* __restrict__ bp_g, int* __restrict__ argd_g,
                    float* __restrict__ out,
                    const int* __restrict__ max_d_p, const int* __restrict__ min_d_p,
                    int B, int T, int S) {
    int b = blockIdx.x;
    int tid = threadIdx.x;
    int s = tid & 63;
    int g = tid >> 6;  // 4 groups of 64
    int D = *max_d_p - *min_d_p + 1;
    if (D > D_MAX) D = D_MAX;   // defensive: never exceed static ring capacity
    int D1 = D + 1;

    __shared__ float Mring[D_MAX][S_MAX];        // M[tau] at slot tau % D
    __shared__ float cring[D_MAX + 1][S_MAX];    // csum[j] at slot j % (D+1)
    __shared__ float durL[D_MAX][S_MAX];         // d-major: conflict-free reads
    __shared__ float transL[S_MAX * S_MAX];
    __shared__ float Arow[S_MAX];
    __shared__ float partV[4][S_MAX];
    __shared__ int   partI[4][S_MAX];
    __shared__ float redV[256];
    __shared__ int   redI[256];

    // load dur (transposed to d-major) and trans into LDS; init csum[0]=0
    for (int i = tid; i < S * D; i += 256) {
        int ss = i / D, dd = i % D;
        durL[dd][ss] = dur_lp_g[i];
    }
    for (int i = tid; i < S * S; i += 256) transL[i] = trans_g[i];
    if (tid < S) cring[0][s] = 0.f;
    __syncthreads();

    const float* obsb = obs_lp + (size_t)b * T * S;
    int* bpb = bp_g + (size_t)b * T * S;
    int* adb = argd_g + (size_t)b * T * S;

    float finV = -INFINITY;   // final flat argmax (only filled at e == T-1)
    int   finI = 0x7fffffff;

    for (int e = 0; e < T; ++e) {
        int slot_e1 = (e + 1) % D1;
        int slot_e = e % D1;
        // csum[e+1] = csum[e] + obs_lp[e]  (overwrites csum[e-D], no longer needed)
        if (tid < S) {
            cring[slot_e1][s] = cring[slot_e][s] + obsb[(size_t)e * S + s];
        }
        __syncthreads();

        // ---- duration recurrence: delta[s,d] = M[e-d,s] + seg + dur_lp[s,d]
        float ce1 = cring[slot_e1][s];
        float bv = -INFINITY; int bi = 0;
        for (int di = g; di < D; di += 4) {
            int d = di + 1;
            int tau = e - d;
            float mval = (tau == -1) ? 0.f : (tau < -1 ? NEGF : Mring[tau % D][s]);
            int start = tau + 1;
            float cb = (start <= 0) ? 0.f : cring[start % D1][s];
            float v = mval + (ce1 - cb) + durL[di][s];
            if (v > bv) { bv = v; bi = di; }  // strict >: first occurrence in group
        }
        partV[g][s] = bv; partI[g][s] = bi;

        // final-step full flat argmax (s-major, d-minor), first occurrence
        if (e == T - 1) {
            float fv = -INFINITY; int fi = 0x7fffffff;
            for (int di = g; di < D; di += 4) {
                int d = di + 1;
                int tau = e - d;
                float mval = (tau == -1) ? 0.f : (tau < -1 ? NEGF : Mring[tau % D][s]);
                int start = tau + 1;
                float cb = (start <= 0) ? 0.f : cring[start % D1][s];
                float v = mval + (ce1 - cb) + durL[di][s];
                int flat = s * D + di;
                if (v > fv || (v == fv && flat < fi)) { fv = v; fi = flat; }
            }
            finV = fv; finI = fi;
        }
        __syncthreads();

        if (tid < S) {
            float A = partV[0][s]; int ad = partI[0][s];
            for (int gg = 1; gg < 4; ++gg) {
                float v = partV[gg][s]; int i2 = partI[gg][s];
                if (v > A || (v == A && i2 < ad)) { A = v; ad = i2; }  // smallest d on tie
            }
            Arow[s] = A;
            adb[(size_t)e * S + s] = ad;
        }
        __syncthreads();

        // ---- transition: M[s] = max_prev A[prev] + trans[prev,s]
        float tb = -INFINITY; int tbi = 0;
        for (int pi = 0; pi < 16; ++pi) {
            int p = g * 16 + pi;
            if (p < S) {
                float v = Arow[p] + transL[p * S + s];
                if (v > tb) { tb = v; tbi = p; }
            }
        }
        partV[g][s] = tb; partI[g][s] = tbi;
        __syncthreads();

        if (tid < S) {
            float M = partV[0][s]; int bp = partI[0][s];
            for (int gg = 1; gg < 4; ++gg) {
                float v = partV[gg][s]; int p2 = partI[gg][s];
                if (v > M || (v == M && p2 < bp)) { M = v; bp = p2; }  // smallest prev on tie
            }
            Mring[e % D][s] = M;   // safe: delta reads of slot e%D were pre-barrier
            bpb[(size_t)e * S + s] = bp;
        }
        __syncthreads();
    }

    // ---- reduce final flat argmax across 256 threads
    redV[tid] = finV; redI[tid] = finI;
    __syncthreads();

    if (tid == 0) {
        float bv2 = redV[0]; int bi2 = redI[0];
        for (int i = 1; i < 256; ++i) {
            if (redV[i] > bv2 || (redV[i] == bv2 && redI[i] < bi2)) { bv2 = redV[i]; bi2 = redI[i]; }
        }
        float score = bv2;
        int s0 = bi2 / D;
        int d0 = bi2 % D + 1;

        // ---- serial backtrace
        float* dec = out + (size_t)b * T;
        int t = T - 1, cs = s0, cd = d0;
        while (t >= 0) {
            int lo = t - cd + 1; if (lo < 0) lo = 0;
            for (int j = lo; j <= t; ++j) dec[j] = (float)cs;
            int tau = t - cd;
            int i = tau; if (i < 0) i = 0; if (i > T - 1) i = T - 1;
            int ps = bpb[(size_t)i * S + cs];
            int pd = adb[(size_t)i * S + ps] + 1;
            t = tau; cs = ps; cd = pd;
        }
        out[(size_t)B * T + b] = score;
    }
}

// ---------------- Host launch ------------------------------------------------
extern "C" void kernel_launch(void* const* d_in, const int* in_sizes, int n_in,
                              void* d_out, int out_size, void* d_ws, size_t ws_size,
                              hipStream_t stream) {
    const float* obs     = (const float*)d_in[0];
    const float* logits  = (const float*)d_in[1];
    const float* means   = (const float*)d_in[2];
    const float* logvars = (const float*)d_in[3];
    const float* shp     = (const float*)d_in[4];
    const float* rate    = (const float*)d_in[5];
    const int*   maxd    = (const int*)d_in[6];
    const int*   mind    = (const int*)d_in[7];
    float* out = (float*)d_out;

    int S  = in_sizes[4];
    int F  = in_sizes[2] / S;
    int BT = in_sizes[0] / F;
    int B  = out_size - BT;      // out_size = B*T + B
    int T  = BT / B;

    // ws layout (4B elements)
    float* ws    = (float*)d_ws;
    float* dur   = ws;                                // S * D_MAX
    float* trans = dur + (size_t)S * D_MAX;           // S * S
    float* ivar  = trans + (size_t)S * S;             // S * F
    float* svl   = ivar + (size_t)S * F;              // S
    float* obslp = svl + S;                           // BT * S
    int*   bp    = (int*)(obslp + (size_t)BT * S);    // BT * S
    int*   ad    = bp + (size_t)BT * S;               // BT * S

    prep_kernel<<<1, 256, 0, stream>>>(logits, logvars, shp, rate, maxd, mind,
                                       dur, trans, ivar, svl, S, F);
    obs_kernel<<<(BT + 3) / 4, dim3(64, 4), 0, stream>>>(obs, means, ivar, svl,
                                                         obslp, BT, S, F);
    viterbi_kernel<<<B, 256, 0, stream>>>(obslp, dur, trans, bp, ad, out,
                                          maxd, mind, B, T, S);
}

// Round 6
// 2120.787 us; speedup vs baseline: 1.7124x; 1.7124x over previous
//
#include <hip/hip_runtime.h>
#include <math.h>

#define S_MAX 64
#define D_MAX 128          // ws sizing
#define RING 128           // LDS ring depth (power of 2)
#define RMASK 127
#define D_SPEC 50          // specialized duration count (runtime-detected)
#define F_MAX 96
#define EPSF 1e-8f
#define NEGF -1e30f

__device__ __forceinline__ float softplusf(float x) {
    return fmaxf(x, 0.0f) + log1pf(expf(-fabsf(x)));
}

// ---------------- Kernel 1: params prep ------------------------------------
__global__ __launch_bounds__(256)
void prep_kernel(const float* __restrict__ logits,
                 const float* __restrict__ log_vars,
                 const float* __restrict__ shape_p,
                 const float* __restrict__ rate_p,
                 const int* __restrict__ max_d_p, const int* __restrict__ min_d_p,
                 float* __restrict__ dur_lp, float* __restrict__ trans,
                 float* __restrict__ ivar, float* __restrict__ svl,
                 int S, int F) {
    int tid = threadIdx.x;
    int min_d = *min_d_p, max_d = *max_d_p;
    int D = max_d - min_d + 1;
    if (D > RMASK) D = RMASK;   // must match viterbi clamp

    for (int s = tid; s < S; s += blockDim.x) {
        float acc = 0.f;
        for (int f = 0; f < F; ++f) {
            float lv = log_vars[s * F + f];
            ivar[s * F + f] = expf(-lv);
            acc += lv;
        }
        svl[s] = acc;
    }
    for (int s = tid; s < S; s += blockDim.x) {
        float a = softplusf(shape_p[s]);
        float r = softplusf(rate_p[s]);
        float lga = lgammaf(a);
        float alr = a * logf(r + EPSF);
        for (int di = 0; di < D; ++di) {
            float dval = (float)(min_d + di);
            float lp = (a - 1.f) * logf(dval + EPSF) - r * dval - lga + alr;
            dur_lp[s * D + di] = logf(expf(lp) + EPSF);
        }
    }
    for (int p = tid; p < S; p += blockDim.x) {
        float m = -INFINITY;
        for (int j = 0; j < S; ++j)
            if (j != p) m = fmaxf(m, logits[p * S + j]);
        float sum = 0.f;
        for (int j = 0; j < S; ++j)
            if (j != p) sum += expf(logits[p * S + j] - m);
        for (int j = 0; j < S; ++j) {
            float v;
            if (j == p) v = NEGF;
            else v = logf(expf(logits[p * S + j] - m) / sum + EPSF);
            trans[p * S + j] = v;
        }
    }
}

// ---------------- Kernel 2: observation log-probs ---------------------------
__global__ __launch_bounds__(256)
void obs_kernel(const float* __restrict__ obs,
                const float* __restrict__ means,
                const float* __restrict__ ivar,
                const float* __restrict__ svl,
                float* __restrict__ obs_lp,
                int BT, int S, int F) {
    __shared__ float sMean[S_MAX * (F_MAX + 1)];
    __shared__ float sIvar[S_MAX * (F_MAX + 1)];
    __shared__ float sObs[4][F_MAX];

    int tid = threadIdx.x + threadIdx.y * 64;
    int PF = F + 1;
    for (int i = tid; i < S * F; i += 256) {
        int ss = i / F, ff = i % F;
        sMean[ss * PF + ff] = means[i];
        sIvar[ss * PF + ff] = ivar[i];
    }
    int row0 = blockIdx.x * 4;
    for (int i = tid; i < 4 * F; i += 256) {
        int r = i / F, f = i % F;
        if (row0 + r < BT) sObs[r][f] = obs[(size_t)(row0 + r) * F + f];
    }
    __syncthreads();

    int s = threadIdx.x;
    int r = threadIdx.y;
    int row = row0 + r;
    if (row >= BT || s >= S) return;

    float quad = 0.f;
    const float* mr = &sMean[s * PF];
    const float* vr = &sIvar[s * PF];
    for (int f = 0; f < F; ++f) {
        float d = sObs[r][f] - mr[f];
        quad = fmaf(d * d, vr[f], quad);
    }
    const float LOG2PI = 1.8378770664093453f;
    obs_lp[(size_t)row * S + s] = -0.5f * (quad + svl[s] + (float)F * LOG2PI);
}

// ---------------- Kernel 3: 1-wave-per-batch Viterbi -------------------------
struct VLds {
    float Mring[RING][S_MAX];    // M[tau] at slot tau & RMASK (lane-private columns)
    float cring[RING][S_MAX];    // csum[j] at slot j & RMASK (lane-private columns)
    float durL[RING][S_MAX];     // generic path only (d-major)
    float transL[S_MAX * S_MAX]; // generic path only
};

// --- specialized step: D==D_SPEC, S==64; no barriers, regs for dur/trans ----
template<bool EDGE>
__device__ __forceinline__ void spec_step(
        int e, int T, int s, VLds& L,
        const float* __restrict__ obsb,
        int* __restrict__ bpb, int* __restrict__ adb,
        const float (&durR)[D_SPEC], const float (&transR)[64],
        float& csum, float& o_cur, float& finV, int& finI) {
    // prefetch next obs row (latency hidden under D-loop)
    float o_nxt = 0.f;
    if (e + 1 < T) o_nxt = obsb[(size_t)(e + 1) * 64 + s];

    csum += o_cur;                       // csum[e+1][s] (sequential, matches cumsum)
    L.cring[(e + 1) & RMASK][s] = csum;
    float ce1 = csum;

    // duration recurrence: two interleaved argmax chains (even/odd di)
    float bv0 = -INFINITY, bv1 = -INFINITY;
    int bi0 = 0, bi1 = 1;
#pragma unroll
    for (int di = 0; di < D_SPEC; di += 2) {
        {
            int tau = e - 1 - di;
            float mval, cb;
            if (EDGE) {
                float mr = L.Mring[tau & RMASK][s];
                mval = (tau == -1) ? 0.f : (tau < -1 ? NEGF : mr);
                int st = tau + 1;
                float cr = L.cring[st & RMASK][s];
                cb = (st <= 0) ? 0.f : cr;
            } else {
                mval = L.Mring[tau & RMASK][s];
                cb = L.cring[(tau + 1) & RMASK][s];
            }
            float v = mval + (ce1 - cb) + durR[di];
            if (v > bv0) { bv0 = v; bi0 = di; }
        }
        {
            int di1 = di + 1;
            int tau = e - 1 - di1;
            float mval, cb;
            if (EDGE) {
                float mr = L.Mring[tau & RMASK][s];
                mval = (tau == -1) ? 0.f : (tau < -1 ? NEGF : mr);
                int st = tau + 1;
                float cr = L.cring[st & RMASK][s];
                cb = (st <= 0) ? 0.f : cr;
            } else {
                mval = L.Mring[tau & RMASK][s];
                cb = L.cring[(tau + 1) & RMASK][s];
            }
            float v = mval + (ce1 - cb) + durR[di1];
            if (v > bv1) { bv1 = v; bi1 = di1; }
        }
    }
    float A; int ad;
    if (bv1 > bv0 || (bv1 == bv0 && bi1 < bi0)) { A = bv1; ad = bi1; }
    else { A = bv0; ad = bi0; }

    if (e == T - 1) { finV = A; finI = s * D_SPEC + ad; }  // flat s-major, min-d tie
    adb[(size_t)e * 64 + s] = ad;

    // transition: M[s] = max_p A[p] + trans[p][s]; cross-lane via shfl (readlane)
    float M0 = -INFINITY, M1 = -INFINITY;
    int p0 = 0, p1 = 1;
#pragma unroll
    for (int p = 0; p < 64; p += 2) {
        float a0 = __shfl(A, p);
        float v0 = a0 + transR[p];
        if (v0 > M0) { M0 = v0; p0 = p; }
        float a1 = __shfl(A, p + 1);
        float v1 = a1 + transR[p + 1];
        if (v1 > M1) { M1 = v1; p1 = p + 1; }
    }
    float M; int bp;
    if (M1 > M0 || (M1 == M0 && p1 < p0)) { M = M1; bp = p1; }
    else { M = M0; bp = p0; }

    L.Mring[e & RMASK][s] = M;   // lane-private column; ring depth 128 > D: no WAR
    bpb[(size_t)e * 64 + s] = bp;
    o_cur = o_nxt;
}

__device__ __forceinline__ void spec_run(
        VLds& L, const float* __restrict__ obsb,
        const float* __restrict__ dur_g, const float* __restrict__ trans_g,
        int* __restrict__ bpb, int* __restrict__ adb,
        int T, int s, float& finV, int& finI) {
    float durR[D_SPEC];
#pragma unroll
    for (int di = 0; di < D_SPEC; ++di) durR[di] = dur_g[s * D_SPEC + di];
    float transR[64];
#pragma unroll
    for (int p = 0; p < 64; ++p) transR[p] = trans_g[p * 64 + s];  // column s

    L.cring[0][s] = 0.f;
    float csum = 0.f;
    float o_cur = (T > 0) ? obsb[s] : 0.f;
    finV = -INFINITY; finI = 0x7fffffff;

    int Dlim = (D_SPEC < T) ? D_SPEC : T;
    int e = 0;
    for (; e < Dlim; ++e)
        spec_step<true>(e, T, s, L, obsb, bpb, adb, durR, transR, csum, o_cur, finV, finI);
    for (; e < T; ++e)
        spec_step<false>(e, T, s, L, obsb, bpb, adb, durR, transR, csum, o_cur, finV, finI);
}

// --- generic fallback: any S<=64, D<=127 (correctness path) -----------------
__device__ void gen_run(
        VLds& L, const float* __restrict__ obsb,
        const float* __restrict__ dur_g, const float* __restrict__ trans_g,
        int* __restrict__ bpb, int* __restrict__ adb,
        int T, int S, int D, int s, float& finV, int& finI) {
    for (int i = s; i < S * D; i += 64) {
        int ss = i / D, dd = i % D;
        L.durL[dd][ss] = dur_g[i];
    }
    for (int i = s; i < S * S; i += 64) L.transL[i] = trans_g[i];
    __syncthreads();  // 1 wave: cheap

    bool act = (s < S);
    if (act) L.cring[0][s] = 0.f;
    float csum = 0.f;
    float o_cur = (act && T > 0) ? obsb[s] : 0.f;
    finV = -INFINITY; finI = 0x7fffffff;

    for (int e = 0; e < T; ++e) {
        float o_nxt = 0.f;
        if (act && e + 1 < T) o_nxt = obsb[(size_t)(e + 1) * S + s];
        csum += o_cur;
        if (act) L.cring[(e + 1) & RMASK][s] = csum;
        float ce1 = csum;

        float bv = -INFINITY; int bi = 0;
#pragma unroll 4
        for (int di = 0; di < D; ++di) {
            int tau = e - 1 - di;
            float mr = L.Mring[tau & RMASK][s & 63];
            float mval = (tau == -1) ? 0.f : (tau < -1 ? NEGF : mr);
            int st = tau + 1;
            float cr = L.cring[st & RMASK][s & 63];
            float cb = (st <= 0) ? 0.f : cr;
            float v = mval + (ce1 - cb) + L.durL[di][s & 63];
            if (v > bv) { bv = v; bi = di; }
        }
        float A = act ? bv : NEGF;
        int ad = bi;
        if (act && e == T - 1) { finV = A; finI = s * D + ad; }
        if (act) adb[(size_t)e * S + s] = ad;

        float M = -INFINITY; int bp = 0;
        for (int p = 0; p < S; ++p) {
            float a = __shfl(A, p);
            float v = a + L.transL[p * S + (s < S ? s : 0)];
            if (v > M) { M = v; bp = p; }
        }
        if (act) {
            L.Mring[e & RMASK][s] = M;
            bpb[(size_t)e * S + s] = bp;
        }
        o_cur = o_nxt;
    }
}

__global__ __launch_bounds__(64)
void viterbi_kernel(const float* __restrict__ obs_lp,
                    const float* __restrict__ dur_g,
                    const float* __restrict__ trans_g,
                    int* __restrict__ bp_g, int* __restrict__ argd_g,
                    float* __restrict__ out,
                    const int* __restrict__ max_d_p, const int* __restrict__ min_d_p,
                    int B, int T, int S) {
    __shared__ VLds L;
    int b = blockIdx.x;
    int s = threadIdx.x;  // 0..63, one wave
    int D = *max_d_p - *min_d_p + 1;
    if (D > RMASK) D = RMASK;

    const float* obsb = obs_lp + (size_t)b * T * S;
    int* bpb = bp_g + (size_t)b * T * S;
    int* adb = argd_g + (size_t)b * T * S;

    float finV; int finI;
    if (D == D_SPEC && S == 64)
        spec_run(L, obsb, dur_g, trans_g, bpb, adb, T, s, finV, finI);
    else
        gen_run(L, obsb, dur_g, trans_g, bpb, adb, T, S, D, s, finV, finI);

    // butterfly reduce (max value, min flat index on tie) across the wave
#pragma unroll
    for (int off = 32; off; off >>= 1) {
        float v2 = __shfl_xor(finV, off);
        int i2 = __shfl_xor(finI, off);
        if (v2 > finV || (v2 == finV && i2 < finI)) { finV = v2; finI = i2; }
    }

    if (s == 0) {
        float score = finV;
        int s0 = finI / D;
        int d0 = finI % D + 1;

        float* dec = out + (size_t)b * T;
        int t = T - 1, cs = s0, cd = d0;
        while (t >= 0) {
            int lo = t - cd + 1; if (lo < 0) lo = 0;
            for (int j = lo; j <= t; ++j) dec[j] = (float)cs;
            int tau = t - cd;
            int i = tau; if (i < 0) i = 0; if (i > T - 1) i = T - 1;
            int ps = bpb[(size_t)i * S + cs];
            int pd = adb[(size_t)i * S + ps] + 1;
            t = tau; cs = ps; cd = pd;
        }
        out[(size_t)B * T + b] = score;
    }
}

// ---------------- Host launch ------------------------------------------------
extern "C" void kernel_launch(void* const* d_in, const int* in_sizes, int n_in,
                              void* d_out, int out_size, void* d_ws, size_t ws_size,
                              hipStream_t stream) {
    const float* obs     = (const float*)d_in[0];
    const float* logits  = (const float*)d_in[1];
    const float* means   = (const float*)d_in[2];
    const float* logvars = (const float*)d_in[3];
    const float* shp     = (const float*)d_in[4];
    const float* rate    = (const float*)d_in[5];
    const int*   maxd    = (const int*)d_in[6];
    const int*   mind    = (const int*)d_in[7];
    float* out = (float*)d_out;

    int S  = in_sizes[4];
    int F  = in_sizes[2] / S;
    int BT = in_sizes[0] / F;
    int B  = out_size - BT;      // out_size = B*T + B
    int T  = BT / B;

    float* ws    = (float*)d_ws;
    float* dur   = ws;                                // S * D_MAX
    float* trans = dur + (size_t)S * D_MAX;           // S * S
    float* ivar  = trans + (size_t)S * S;             // S * F
    float* svl   = ivar + (size_t)S * F;              // S
    float* obslp = svl + S;                           // BT * S
    int*   bp    = (int*)(obslp + (size_t)BT * S);    // BT * S
    int*   ad    = bp + (size_t)BT * S;               // BT * S

    prep_kernel<<<1, 256, 0, stream>>>(logits, logvars, shp, rate, maxd, mind,
                                       dur, trans, ivar, svl, S, F);
    obs_kernel<<<(BT + 3) / 4, dim3(64, 4), 0, stream>>>(obs, means, ivar, svl,
                                                         obslp, BT, S, F);
    viterbi_kernel<<<B, 64, 0, stream>>>(obslp, dur, trans, bp, ad, out,
                                         maxd, mind, B, T, S);
}

// Round 9
// 1448.769 us; speedup vs baseline: 2.5067x; 1.4639x over previous
//
#include <hip/hip_runtime.h>
#include <math.h>

#define S_MAX 64
#define D_MAX 128          // ws sizing
#define RING 128           // LDS ring depth (generic path, power of 2)
#define RMASK 127
#define D_SPEC 50          // specialized duration count (runtime-detected)
#define F_MAX 96
#define OBS_ROWS 16
#define EPSF 1e-8f
#define NEGF -1e30f

__device__ __forceinline__ float softplusf(float x) {
    return fmaxf(x, 0.0f) + log1pf(expf(-fabsf(x)));
}

// ---------------- Kernel 1: params prep ------------------------------------
__global__ __launch_bounds__(256)
void prep_kernel(const float* __restrict__ logits,
                 const float* __restrict__ log_vars,
                 const float* __restrict__ shape_p,
                 const float* __restrict__ rate_p,
                 const int* __restrict__ max_d_p, const int* __restrict__ min_d_p,
                 float* __restrict__ dur_lp, float* __restrict__ trans,
                 float* __restrict__ ivar, float* __restrict__ svl,
                 int S, int F) {
    int tid = threadIdx.x;
    int min_d = *min_d_p, max_d = *max_d_p;
    int D = max_d - min_d + 1;
    if (D > RMASK) D = RMASK;   // must match viterbi clamp

    for (int s = tid; s < S; s += blockDim.x) {
        float acc = 0.f;
        for (int f = 0; f < F; ++f) {
            float lv = log_vars[s * F + f];
            ivar[s * F + f] = expf(-lv);
            acc += lv;
        }
        svl[s] = acc;
    }
    for (int s = tid; s < S; s += blockDim.x) {
        float a = softplusf(shape_p[s]);
        float r = softplusf(rate_p[s]);
        float lga = lgammaf(a);
        float alr = a * logf(r + EPSF);
        for (int di = 0; di < D; ++di) {
            float dval = (float)(min_d + di);
            float lp = (a - 1.f) * logf(dval + EPSF) - r * dval - lga + alr;
            dur_lp[s * D + di] = logf(expf(lp) + EPSF);
        }
    }
    for (int p = tid; p < S; p += blockDim.x) {
        float m = -INFINITY;
        for (int j = 0; j < S; ++j)
            if (j != p) m = fmaxf(m, logits[p * S + j]);
        float sum = 0.f;
        for (int j = 0; j < S; ++j)
            if (j != p) sum += expf(logits[p * S + j] - m);
        for (int j = 0; j < S; ++j) {
            float v;
            if (j == p) v = NEGF;
            else v = logf(expf(logits[p * S + j] - m) / sum + EPSF);
            trans[p * S + j] = v;
        }
    }
}

// ---------------- Kernel 2: observation log-probs ---------------------------
// OBS_ROWS rows per block: amortizes the 41KB means/ivar LDS staging.
__global__ __launch_bounds__(256)
void obs_kernel(const float* __restrict__ obs,
                const float* __restrict__ means,
                const float* __restrict__ ivar,
                const float* __restrict__ svl,
                float* __restrict__ obs_lp,
                int BT, int S, int F) {
    __shared__ float sMean[S_MAX * (F_MAX + 1)];
    __shared__ float sIvar[S_MAX * (F_MAX + 1)];
    __shared__ float sObs[OBS_ROWS][F_MAX];

    int tid = threadIdx.x + threadIdx.y * 64;
    int PF = F + 1;
    for (int i = tid; i < S * F; i += 256) {
        int ss = i / F, ff = i % F;
        sMean[ss * PF + ff] = means[i];
        sIvar[ss * PF + ff] = ivar[i];
    }
    int row0 = blockIdx.x * OBS_ROWS;
    for (int i = tid; i < OBS_ROWS * F; i += 256) {
        int r = i / F, f = i % F;
        if (row0 + r < BT) sObs[r][f] = obs[(size_t)(row0 + r) * F + f];
    }
    __syncthreads();

    int s = threadIdx.x;
    if (s >= S) return;
    const float* mr = &sMean[s * PF];
    const float* vr = &sIvar[s * PF];
    const float LOG2PI = 1.8378770664093453f;
    float base = svl[s] + (float)F * LOG2PI;

    for (int r = threadIdx.y; r < OBS_ROWS; r += 4) {
        int row = row0 + r;
        if (row >= BT) break;
        float quad = 0.f;
        for (int f = 0; f < F; ++f) {
            float d = sObs[r][f] - mr[f];
            quad = fmaf(d * d, vr[f], quad);
        }
        obs_lp[(size_t)row * S + s] = -0.5f * (quad + base);
    }
}

// ---------------- Kernel 3: 1-wave-per-batch Viterbi -------------------------
struct VLds {     // generic path only; spec path is fully register-resident
    float Mring[RING][S_MAX];
    float cring[RING][S_MAX];
    float durL[RING][S_MAX];
    float transL[S_MAX * S_MAX];
};

__device__ __forceinline__ float lane_bcast(float v, int lane) {
    return __uint_as_float(__builtin_amdgcn_readlane(__float_as_uint(v), lane));
}

// --- specialized run: D==50, S==64; zero LDS, zero barriers -----------------
// Lane s owns column s. History rings live in per-lane REGISTERS:
//   mring[i] = M[e-1-i][s], cring[i] = csum[max(e-i,0)][s]
// Pre-init mring={0,NEG,...}, cring={0,...} encodes M[-1]=0, M[<-1]=NEG,
// csum[clip(start,0)]=0  ->  no edge selects anywhere.
__device__ __forceinline__ void spec_run(
        const float* __restrict__ obsb,
        const float* __restrict__ dur_g, const float* __restrict__ trans_g,
        int* __restrict__ bpb, int* __restrict__ adb,
        int T, int s, float& finV, int& finI) {
    float durR[D_SPEC];
#pragma unroll
    for (int di = 0; di < D_SPEC; ++di) durR[di] = dur_g[s * D_SPEC + di];
    float transR[64];
#pragma unroll
    for (int p = 0; p < 64; ++p) transR[p] = trans_g[p * 64 + s];  // column s

    float mring[D_SPEC];
    float cring[D_SPEC];
    mring[0] = 0.f;        // M[-1] = 0 (start state)
#pragma unroll
    for (int i = 1; i < D_SPEC; ++i) mring[i] = NEGF;   // M[<-1] = NEG
#pragma unroll
    for (int i = 0; i < D_SPEC; ++i) cring[i] = 0.f;    // csum[<=0] = 0

    float csum = 0.f;
    float o_cur = (T > 0) ? obsb[s] : 0.f;
    finV = -INFINITY; finI = 0x7fffffff;

    for (int e = 0; e < T; ++e) {
        float o_nxt = 0.f;
        if (e + 1 < T) o_nxt = obsb[(size_t)(e + 1) * 64 + s];

        csum += o_cur;                 // csum[e+1]  (sequential prefix sum)
        float ce1 = csum;

        // ---- duration recurrence: v = (M[e-1-di] + (ce1 - csum[e-di])) + dur[di]
        float bv0 = -INFINITY, bv1 = -INFINITY;
        int bi0 = 0, bi1 = 1;
#pragma unroll
        for (int di = 0; di < D_SPEC; di += 2) {
            float v0 = (mring[di] + (ce1 - cring[di])) + durR[di];
            if (v0 > bv0) { bv0 = v0; bi0 = di; }
            float v1 = (mring[di + 1] + (ce1 - cring[di + 1])) + durR[di + 1];
            if (v1 > bv1) { bv1 = v1; bi1 = di + 1; }
        }
        float A; int ad;
        if (bv1 > bv0 || (bv1 == bv0 && bi1 < bi0)) { A = bv1; ad = bi1; }
        else { A = bv0; ad = bi0; }

        if (e == T - 1) { finV = A; finI = s * D_SPEC + ad; }  // flat s-major
        adb[(size_t)e * 64 + s] = ad;

        // ---- transition: M[s] = max_p A[p] + trans[p][s]; readlane broadcast
        float M0 = -INFINITY, M1 = -INFINITY;
        int p0 = 0, p1 = 1;
#pragma unroll
        for (int p = 0; p < 64; p += 2) {
            float a0 = lane_bcast(A, p);
            float v0 = a0 + transR[p];
            if (v0 > M0) { M0 = v0; p0 = p; }
            float a1 = lane_bcast(A, p + 1);
            float v1 = a1 + transR[p + 1];
            if (v1 > M1) { M1 = v1; p1 = p + 1; }
        }
        float M; int bp;
        if (M1 > M0 || (M1 == M0 && p1 < p0)) { M = M1; bp = p1; }
        else { M = M0; bp = p0; }
        bpb[(size_t)e * 64 + s] = bp;

        // ---- shift register rings (static indices -> pure v_mov renames)
#pragma unroll
        for (int i = D_SPEC - 1; i >= 1; --i) {
            mring[i] = mring[i - 1];
            cring[i] = cring[i - 1];
        }
        mring[0] = M;
        cring[0] = ce1;
        o_cur = o_nxt;
    }
}

// --- generic fallback: any S<=64, D<=127 (correctness path, LDS rings) ------
__device__ void gen_run(
        VLds& L, const float* __restrict__ obsb,
        const float* __restrict__ dur_g, const float* __restrict__ trans_g,
        int* __restrict__ bpb, int* __restrict__ adb,
        int T, int S, int D, int s, float& finV, int& finI) {
    for (int i = s; i < S * D; i += 64) {
        int ss = i / D, dd = i % D;
        L.durL[dd][ss] = dur_g[i];
    }
    for (int i = s; i < S * S; i += 64) L.transL[i] = trans_g[i];
    __syncthreads();

    bool act = (s < S);
    if (act) L.cring[0][s] = 0.f;
    float csum = 0.f;
    float o_cur = (act && T > 0) ? obsb[s] : 0.f;
    finV = -INFINITY; finI = 0x7fffffff;

    for (int e = 0; e < T; ++e) {
        float o_nxt = 0.f;
        if (act && e + 1 < T) o_nxt = obsb[(size_t)(e + 1) * S + s];
        csum += o_cur;
        if (act) L.cring[(e + 1) & RMASK][s] = csum;
        float ce1 = csum;

        float bv = -INFINITY; int bi = 0;
#pragma unroll 4
        for (int di = 0; di < D; ++di) {
            int tau = e - 1 - di;
            float mr = L.Mring[tau & RMASK][s & 63];
            float mval = (tau == -1) ? 0.f : (tau < -1 ? NEGF : mr);
            int st = tau + 1;
            float cr = L.cring[st & RMASK][s & 63];
            float cb = (st <= 0) ? 0.f : cr;
            float v = mval + (ce1 - cb) + L.durL[di][s & 63];
            if (v > bv) { bv = v; bi = di; }
        }
        float A = act ? bv : NEGF;
        int ad = bi;
        if (act && e == T - 1) { finV = A; finI = s * D + ad; }
        if (act) adb[(size_t)e * S + s] = ad;

        float M = -INFINITY; int bp = 0;
        for (int p = 0; p < S; ++p) {
            float a = __shfl(A, p);
            float v = a + L.transL[p * S + (s < S ? s : 0)];
            if (v > M) { M = v; bp = p; }
        }
        if (act) {
            L.Mring[e & RMASK][s] = M;
            bpb[(size_t)e * S + s] = bp;
        }
        o_cur = o_nxt;
    }
}

__global__ __launch_bounds__(64, 1)   // 1 wave/EU target: full 512-VGPR budget
void viterbi_kernel(const float* __restrict__ obs_lp,
                    const float* __restrict__ dur_g,
                    const float* __restrict__ trans_g,
                    int* __restrict__ bp_g, int* __restrict__ argd_g,
                    float* __restrict__ out,
                    const int* __restrict__ max_d_p, const int* __restrict__ min_d_p,
                    int B, int T, int S) {
    __shared__ VLds L;
    int b = blockIdx.x;
    int s = threadIdx.x;  // 0..63, one wave
    int D = *max_d_p - *min_d_p + 1;
    if (D > RMASK) D = RMASK;

    const float* obsb = obs_lp + (size_t)b * T * S;
    int* bpb = bp_g + (size_t)b * T * S;
    int* adb = argd_g + (size_t)b * T * S;

    float finV; int finI;
    if (D == D_SPEC && S == 64)
        spec_run(obsb, dur_g, trans_g, bpb, adb, T, s, finV, finI);
    else
        gen_run(L, obsb, dur_g, trans_g, bpb, adb, T, S, D, s, finV, finI);

    // butterfly reduce (max value, min flat index on tie) across the wave
#pragma unroll
    for (int off = 32; off; off >>= 1) {
        float v2 = __shfl_xor(finV, off);
        int i2 = __shfl_xor(finI, off);
        if (v2 > finV || (v2 == finV && i2 < finI)) { finV = v2; finI = i2; }
    }

    if (s == 0) {
        float score = finV;
        int s0 = finI / D;
        int d0 = finI % D + 1;

        float* dec = out + (size_t)b * T;
        int t = T - 1, cs = s0, cd = d0;
        while (t >= 0) {
            int lo = t - cd + 1; if (lo < 0) lo = 0;
            for (int j = lo; j <= t; ++j) dec[j] = (float)cs;
            int tau = t - cd;
            int i = tau; if (i < 0) i = 0; if (i > T - 1) i = T - 1;
            int ps = bpb[(size_t)i * S + cs];
            int pd = adb[(size_t)i * S + ps] + 1;
            t = tau; cs = ps; cd = pd;
        }
        out[(size_t)B * T + b] = score;
    }
}

// ---------------- Host launch ------------------------------------------------
extern "C" void kernel_launch(void* const* d_in, const int* in_sizes, int n_in,
                              void* d_out, int out_size, void* d_ws, size_t ws_size,
                              hipStream_t stream) {
    const float* obs     = (const float*)d_in[0];
    const float* logits  = (const float*)d_in[1];
    const float* means   = (const float*)d_in[2];
    const float* logvars = (const float*)d_in[3];
    const float* shp     = (const float*)d_in[4];
    const float* rate    = (const float*)d_in[5];
    const int*   maxd    = (const int*)d_in[6];
    const int*   mind    = (const int*)d_in[7];
    float* out = (float*)d_out;

    int S  = in_sizes[4];
    int F  = in_sizes[2] / S;
    int BT = in_sizes[0] / F;
    int B  = out_size - BT;      // out_size = B*T + B
    int T  = BT / B;

    float* ws    = (float*)d_ws;
    float* dur   = ws;                                // S * D_MAX
    float* trans = dur + (size_t)S * D_MAX;           // S * S
    float* ivar  = trans + (size_t)S * S;             // S * F
    float* svl   = ivar + (size_t)S * F;              // S
    float* obslp = svl + S;                           // BT * S
    int*   bp    = (int*)(obslp + (size_t)BT * S);    // BT * S
    int*   ad    = bp + (size_t)BT * S;               // BT * S

    prep_kernel<<<1, 256, 0, stream>>>(logits, logvars, shp, rate, maxd, mind,
                                       dur, trans, ivar, svl, S, F);
    obs_kernel<<<(BT + OBS_ROWS - 1) / OBS_ROWS, dim3(64, 4), 0, stream>>>(
        obs, means, ivar, svl, obslp, BT, S, F);
    viterbi_kernel<<<B, 64, 0, stream>>>(obslp, dur, trans, bp, ad, out,
                                         maxd, mind, B, T, S);
}

// Round 10
// 1378.516 us; speedup vs baseline: 2.6344x; 1.0510x over previous
//
#include <hip/hip_runtime.h>
#include <math.h>

#define S_MAX 64
#define D_MAX 128          // ws sizing
#define RING 128           // LDS ring depth (generic path, power of 2)
#define RMASK 127
#define D_SPEC 50          // specialized duration count (runtime-detected)
#define F_MAX 96
#define OBS_ROWS 16
#define EPSF 1e-8f
#define NEGF -1e30f

__device__ __forceinline__ float softplusf(float x) {
    return fmaxf(x, 0.0f) + log1pf(expf(-fabsf(x)));
}

// ---------------- Kernel 1: params prep ------------------------------------
__global__ __launch_bounds__(256)
void prep_kernel(const float* __restrict__ logits,
                 const float* __restrict__ log_vars,
                 const float* __restrict__ shape_p,
                 const float* __restrict__ rate_p,
                 const int* __restrict__ max_d_p, const int* __restrict__ min_d_p,
                 float* __restrict__ dur_lp, float* __restrict__ trans,
                 float* __restrict__ ivar, float* __restrict__ svl,
                 int S, int F) {
    int tid = threadIdx.x;
    int min_d = *min_d_p, max_d = *max_d_p;
    int D = max_d - min_d + 1;
    if (D > RMASK) D = RMASK;   // must match viterbi clamp

    for (int s = tid; s < S; s += blockDim.x) {
        float acc = 0.f;
        for (int f = 0; f < F; ++f) {
            float lv = log_vars[s * F + f];
            ivar[s * F + f] = expf(-lv);
            acc += lv;
        }
        svl[s] = acc;
    }
    for (int s = tid; s < S; s += blockDim.x) {
        float a = softplusf(shape_p[s]);
        float r = softplusf(rate_p[s]);
        float lga = lgammaf(a);
        float alr = a * logf(r + EPSF);
        for (int di = 0; di < D; ++di) {
            float dval = (float)(min_d + di);
            float lp = (a - 1.f) * logf(dval + EPSF) - r * dval - lga + alr;
            dur_lp[s * D + di] = logf(expf(lp) + EPSF);
        }
    }
    for (int p = tid; p < S; p += blockDim.x) {
        float m = -INFINITY;
        for (int j = 0; j < S; ++j)
            if (j != p) m = fmaxf(m, logits[p * S + j]);
        float sum = 0.f;
        for (int j = 0; j < S; ++j)
            if (j != p) sum += expf(logits[p * S + j] - m);
        for (int j = 0; j < S; ++j) {
            float v;
            if (j == p) v = NEGF;
            else v = logf(expf(logits[p * S + j] - m) / sum + EPSF);
            trans[p * S + j] = v;
        }
    }
}

// ---------------- Kernel 2: observation log-probs ---------------------------
__global__ __launch_bounds__(256)
void obs_kernel(const float* __restrict__ obs,
                const float* __restrict__ means,
                const float* __restrict__ ivar,
                const float* __restrict__ svl,
                float* __restrict__ obs_lp,
                int BT, int S, int F) {
    __shared__ float sMean[S_MAX * (F_MAX + 1)];
    __shared__ float sIvar[S_MAX * (F_MAX + 1)];
    __shared__ float sObs[OBS_ROWS][F_MAX];

    int tid = threadIdx.x + threadIdx.y * 64;
    int PF = F + 1;
    for (int i = tid; i < S * F; i += 256) {
        int ss = i / F, ff = i % F;
        sMean[ss * PF + ff] = means[i];
        sIvar[ss * PF + ff] = ivar[i];
    }
    int row0 = blockIdx.x * OBS_ROWS;
    for (int i = tid; i < OBS_ROWS * F; i += 256) {
        int r = i / F, f = i % F;
        if (row0 + r < BT) sObs[r][f] = obs[(size_t)(row0 + r) * F + f];
    }
    __syncthreads();

    int s = threadIdx.x;
    if (s >= S) return;
    const float* mr = &sMean[s * PF];
    const float* vr = &sIvar[s * PF];
    const float LOG2PI = 1.8378770664093453f;
    float base = svl[s] + (float)F * LOG2PI;

    for (int r = threadIdx.y; r < OBS_ROWS; r += 4) {
        int row = row0 + r;
        if (row >= BT) break;
        float quad = 0.f;
        for (int f = 0; f < F; ++f) {
            float d = sObs[r][f] - mr[f];
            quad = fmaf(d * d, vr[f], quad);
        }
        obs_lp[(size_t)row * S + s] = -0.5f * (quad + base);
    }
}

__device__ __forceinline__ float lane_bcast(float v, int lane) {
    return __uint_as_float(__builtin_amdgcn_readlane(__float_as_uint(v), lane));
}

// ---------------- Kernel 3a: SPECIALIZED Viterbi (D==50, S==64) -------------
// One wave per batch. Lane s owns state s. History rings in REGISTERS
// (100 VGPRs), dur in registers (50), trans in 16KB LDS (the only LDS).
// Ring pre-init encodes M[-1]=0, M[<-1]=NEG, csum[<=0]=0 -> no edge selects.
__global__ __launch_bounds__(64, 1)   // 1 wave/EU: full VGPR budget
void viterbi_spec(const float* __restrict__ obs_lp,
                  const float* __restrict__ dur_g,
                  const float* __restrict__ trans_g,
                  int* __restrict__ bp_g, int* __restrict__ argd_g,
                  float* __restrict__ out,
                  const int* __restrict__ max_d_p, const int* __restrict__ min_d_p,
                  int B, int T, int S) {
    int D = *max_d_p - *min_d_p + 1;
    if (!(D == D_SPEC && S == 64)) return;   // viterbi_gen handles other shapes

    __shared__ float transL[64 * 64];        // 16 KB: trans[p][s], row-major
    int b = blockIdx.x;
    int s = threadIdx.x;                     // 0..63

    for (int i = s; i < 64 * 64; i += 64) transL[i] = trans_g[i];
    __syncthreads();                         // one-time; also fences LDS writes

    float durR[D_SPEC];
#pragma unroll
    for (int di = 0; di < D_SPEC; ++di) durR[di] = dur_g[s * D_SPEC + di];

    float mring[D_SPEC];                     // mring[i] = M[e-1-i][s]
    float cring[D_SPEC];                     // cring[i] = csum[max(e-i,0)][s]
    mring[0] = 0.f;
#pragma unroll
    for (int i = 1; i < D_SPEC; ++i) mring[i] = NEGF;
#pragma unroll
    for (int i = 0; i < D_SPEC; ++i) cring[i] = 0.f;

    const float* obsb = obs_lp + (size_t)b * T * 64;
    int* bpb = bp_g + (size_t)b * T * 64;
    int* adb = argd_g + (size_t)b * T * 64;
    const float* tc = &transL[s];            // column s, stride 64 floats

    float csum = 0.f;
    float o_cur = (T > 0) ? obsb[s] : 0.f;
    float finV = -INFINITY; int finI = 0x7fffffff;

    for (int e = 0; e < T; ++e) {
        float o_nxt = (e + 1 < T) ? obsb[(size_t)(e + 1) * 64 + s] : 0.f;

        csum += o_cur;                       // csum[e+1] (sequential prefix sum)
        float ce1 = csum;

        // ---- duration argmax: v = (M[e-1-di] + (ce1 - csum[e-di])) + dur[di]
        float bv0 = -INFINITY, bv1 = -INFINITY;
        int bi0 = 0, bi1 = 1;
#pragma unroll
        for (int di = 0; di < D_SPEC; di += 2) {
            float v0 = (mring[di] + (ce1 - cring[di])) + durR[di];
            if (v0 > bv0) { bv0 = v0; bi0 = di; }
            float v1 = (mring[di + 1] + (ce1 - cring[di + 1])) + durR[di + 1];
            if (v1 > bv1) { bv1 = v1; bi1 = di + 1; }
        }
        float A; int ad;
        if (bv1 > bv0 || (bv1 == bv0 && bi1 < bi0)) { A = bv1; ad = bi1; }
        else { A = bv0; ad = bi0; }

        if (e == T - 1) { finV = A; finI = s * D_SPEC + ad; }  // flat s-major
        adb[(size_t)e * 64 + s] = ad;

        // ---- transition: M[s] = max_p A[p] + trans[p][s]
        // A[p] via readlane (VALU), trans[p][s] via LDS imm-offset reads
        float M0 = -INFINITY, M1 = -INFINITY;
        int p0 = 0, p1 = 1;
#pragma unroll
        for (int p = 0; p < 64; p += 2) {
            float v0 = lane_bcast(A, p) + tc[p * 64];
            if (v0 > M0) { M0 = v0; p0 = p; }
            float v1 = lane_bcast(A, p + 1) + tc[(p + 1) * 64];
            if (v1 > M1) { M1 = v1; p1 = p + 1; }
        }
        float M; int bp;
        if (M1 > M0 || (M1 == M0 && p1 < p0)) { M = M1; bp = p1; }
        else { M = M0; bp = p0; }
        bpb[(size_t)e * 64 + s] = bp;

        // ---- shift register rings (static indices -> register renames)
#pragma unroll
        for (int i = D_SPEC - 1; i >= 1; --i) {
            mring[i] = mring[i - 1];
            cring[i] = cring[i - 1];
        }
        mring[0] = M;
        cring[0] = ce1;
        o_cur = o_nxt;
    }

    // ---- wave-wide final argmax (max value, min flat index on tie)
#pragma unroll
    for (int off = 32; off; off >>= 1) {
        float v2 = __shfl_xor(finV, off);
        int i2 = __shfl_xor(finI, off);
        if (v2 > finV || (v2 == finV && i2 < finI)) { finV = v2; finI = i2; }
    }

    if (s == 0) {
        float score = finV;
        int s0 = finI / D_SPEC;
        int d0 = finI % D_SPEC + 1;

        float* dec = out + (size_t)b * T;
        int t = T - 1, cs = s0, cd = d0;
        while (t >= 0) {
            int lo = t - cd + 1; if (lo < 0) lo = 0;
            for (int j = lo; j <= t; ++j) dec[j] = (float)cs;
            int tau = t - cd;
            int i = tau; if (i < 0) i = 0; if (i > T - 1) i = T - 1;
            int ps = bpb[(size_t)i * 64 + cs];
            int pd = adb[(size_t)i * 64 + ps] + 1;
            t = tau; cs = ps; cd = pd;
        }
        out[(size_t)B * T + b] = score;
    }
}

// ---------------- Kernel 3b: GENERIC Viterbi (any S<=64, D<=127) ------------
struct VLds {
    float Mring[RING][S_MAX];
    float cring[RING][S_MAX];
    float durL[RING][S_MAX];
    float transL[S_MAX * S_MAX];
};

__global__ __launch_bounds__(64)
void viterbi_gen(const float* __restrict__ obs_lp,
                 const float* __restrict__ dur_g,
                 const float* __restrict__ trans_g,
                 int* __restrict__ bp_g, int* __restrict__ argd_g,
                 float* __restrict__ out,
                 const int* __restrict__ max_d_p, const int* __restrict__ min_d_p,
                 int B, int T, int S) {
    int D = *max_d_p - *min_d_p + 1;
    if (D == D_SPEC && S == 64) return;      // viterbi_spec handled it
    if (D > RMASK) D = RMASK;

    __shared__ VLds L;
    int b = blockIdx.x;
    int s = threadIdx.x;

    for (int i = s; i < S * D; i += 64) {
        int ss = i / D, dd = i % D;
        L.durL[dd][ss] = dur_g[i];
    }
    for (int i = s; i < S * S; i += 64) L.transL[i] = trans_g[i];
    __syncthreads();

    const float* obsb = obs_lp + (size_t)b * T * S;
    int* bpb = bp_g + (size_t)b * T * S;
    int* adb = argd_g + (size_t)b * T * S;

    bool act = (s < S);
    if (act) L.cring[0][s] = 0.f;
    float csum = 0.f;
    float o_cur = (act && T > 0) ? obsb[s] : 0.f;
    float finV = -INFINITY; int finI = 0x7fffffff;

    for (int e = 0; e < T; ++e) {
        float o_nxt = 0.f;
        if (act && e + 1 < T) o_nxt = obsb[(size_t)(e + 1) * S + s];
        csum += o_cur;
        if (act) L.cring[(e + 1) & RMASK][s] = csum;
        float ce1 = csum;

        float bv = -INFINITY; int bi = 0;
#pragma unroll 4
        for (int di = 0; di < D; ++di) {
            int tau = e - 1 - di;
            float mr = L.Mring[tau & RMASK][s & 63];
            float mval = (tau == -1) ? 0.f : (tau < -1 ? NEGF : mr);
            int st = tau + 1;
            float cr = L.cring[st & RMASK][s & 63];
            float cb = (st <= 0) ? 0.f : cr;
            float v = mval + (ce1 - cb) + L.durL[di][s & 63];
            if (v > bv) { bv = v; bi = di; }
        }
        float A = act ? bv : NEGF;
        int ad = bi;
        if (act && e == T - 1) { finV = A; finI = s * D + ad; }
        if (act) adb[(size_t)e * S + s] = ad;

        float M = -INFINITY; int bp = 0;
        for (int p = 0; p < S; ++p) {
            float a = __shfl(A, p);
            float v = a + L.transL[p * S + (s < S ? s : 0)];
            if (v > M) { M = v; bp = p; }
        }
        if (act) {
            L.Mring[e & RMASK][s] = M;
            bpb[(size_t)e * S + s] = bp;
        }
        o_cur = o_nxt;
    }

#pragma unroll
    for (int off = 32; off; off >>= 1) {
        float v2 = __shfl_xor(finV, off);
        int i2 = __shfl_xor(finI, off);
        if (v2 > finV || (v2 == finV && i2 < finI)) { finV = v2; finI = i2; }
    }

    if (s == 0) {
        float score = finV;
        int s0 = finI / D;
        int d0 = finI % D + 1;

        float* dec = out + (size_t)b * T;
        int t = T - 1, cs = s0, cd = d0;
        while (t >= 0) {
            int lo = t - cd + 1; if (lo < 0) lo = 0;
            for (int j = lo; j <= t; ++j) dec[j] = (float)cs;
            int tau = t - cd;
            int i = tau; if (i < 0) i = 0; if (i > T - 1) i = T - 1;
            int ps = bpb[(size_t)i * S + cs];
            int pd = adb[(size_t)i * S + ps] + 1;
            t = tau; cs = ps; cd = pd;
        }
        out[(size_t)B * T + b] = score;
    }
}

// ---------------- Host launch ------------------------------------------------
extern "C" void kernel_launch(void* const* d_in, const int* in_sizes, int n_in,
                              void* d_out, int out_size, void* d_ws, size_t ws_size,
                              hipStream_t stream) {
    const float* obs     = (const float*)d_in[0];
    const float* logits  = (const float*)d_in[1];
    const float* means   = (const float*)d_in[2];
    const float* logvars = (const float*)d_in[3];
    const float* shp     = (const float*)d_in[4];
    const float* rate    = (const float*)d_in[5];
    const int*   maxd    = (const int*)d_in[6];
    const int*   mind    = (const int*)d_in[7];
    float* out = (float*)d_out;

    int S  = in_sizes[4];
    int F  = in_sizes[2] / S;
    int BT = in_sizes[0] / F;
    int B  = out_size - BT;      // out_size = B*T + B
    int T  = BT / B;

    float* ws    = (float*)d_ws;
    float* dur   = ws;                                // S * D_MAX
    float* trans = dur + (size_t)S * D_MAX;           // S * S
    float* ivar  = trans + (size_t)S * S;             // S * F
    float* svl   = ivar + (size_t)S * F;              // S
    float* obslp = svl + S;                           // BT * S
    int*   bp    = (int*)(obslp + (size_t)BT * S);    // BT * S
    int*   ad    = bp + (size_t)BT * S;               // BT * S

    prep_kernel<<<1, 256, 0, stream>>>(logits, logvars, shp, rate, maxd, mind,
                                       dur, trans, ivar, svl, S, F);
    obs_kernel<<<(BT + OBS_ROWS - 1) / OBS_ROWS, dim3(64, 4), 0, stream>>>(
        obs, means, ivar, svl, obslp, BT, S, F);
    // Both launched every call (graph-capture-safe); device-side shape guards
    // make exactly one do the work.
    viterbi_spec<<<B, 64, 0, stream>>>(obslp, dur, trans, bp, ad, out,
                                       maxd, mind, B, T, S);
    viterbi_gen<<<B, 64, 0, stream>>>(obslp, dur, trans, bp, ad, out,
                                      maxd, mind, B, T, S);
}